// Round 3
// baseline (5685.847 us; speedup 1.0000x reference)
//
#include <hip/hip_runtime.h>

typedef unsigned short bf16_t;
typedef uint2  __attribute__((may_alias)) uint2_a;
typedef uint4  __attribute__((may_alias)) uint4_a;
typedef float4 __attribute__((may_alias)) float4_a;

constexpr int kS  = 256;
constexpr int kR  = 384;
constexpr int kCM = 256;
constexpr int kCZ = 128;
constexpr int kC  = 32;
constexpr int kH  = 8;
constexpr int kP  = kR * kR;        // 147456
constexpr int kM  = kS * kR;        // 98304
constexpr int kSC = 128;            // s per chunk
constexpr int kNCH = kS / kSC;      // 2 chunks
constexpr int kMC = kSC * kR;       // 49152 msa rows per chunk
constexpr int kPC = kSC * kP / kS;  // 73728 pair rows per chunk

#define EPSF 1e-5f
#define SCALEF 0.17677669529663687f

__device__ __forceinline__ float bf2f(bf16_t u) {
  return __uint_as_float(((unsigned int)u) << 16);
}
__device__ __forceinline__ bf16_t f2bf(float f) {
  unsigned int u = __float_as_uint(f);
  u += 0x7fffu + ((u >> 16) & 1u);
  return (bf16_t)(u >> 16);
}
__device__ __forceinline__ void bfp2(unsigned int w, float* d) {
  d[0] = __uint_as_float(w << 16);
  d[1] = __uint_as_float(w & 0xffff0000u);
}
__device__ __forceinline__ void bf8load(const bf16_t* p, float* d) {
  uint4_a r = *(const uint4_a*)p;
  bfp2(r.x, d + 0); bfp2(r.y, d + 2); bfp2(r.z, d + 4); bfp2(r.w, d + 6);
}

// ---------------- K1: pair row stats (fp32 input) ----------------
__global__ __launch_bounds__(64) void k_pair_stats(const float* __restrict__ pair,
                                                   float* __restrict__ mu,
                                                   float* __restrict__ rstd) {
  int p = blockIdx.x;
  int t = threadIdx.x;
  float x0 = pair[(size_t)p * kCZ + t];
  float x1 = pair[(size_t)p * kCZ + 64 + t];
  float s1 = x0 + x1;
  float s2 = x0 * x0 + x1 * x1;
#pragma unroll
  for (int off = 32; off > 0; off >>= 1) {
    s1 += __shfl_xor(s1, off);
    s2 += __shfl_xor(s2, off);
  }
  if (t == 0) {
    float m = s1 * (1.0f / kCZ);
    float v = s2 * (1.0f / kCZ) - m * m;
    mu[p] = m;
    rstd[p] = rsqrtf(fmaxf(v, 0.0f) + EPSF);
  }
}

// ---------------- K2: msa LN (fp32 or bf16 src -> bf16 dst, fp32 math) ----------------
__global__ __launch_bounds__(64) void k_msa_ln(const float* __restrict__ src_f,
                                               const bf16_t* __restrict__ src_b,
                                               bf16_t* __restrict__ dst,
                                               const float* __restrict__ wall,
                                               const float* __restrict__ ball,
                                               int head, int first) {
  int row = blockIdx.x;
  int t = threadIdx.x;
  float x[4];
  float s1 = 0.f, s2 = 0.f;
#pragma unroll
  for (int j = 0; j < 4; ++j) {
    size_t idx = (size_t)row * kCM + 64 * j + t;
    x[j] = first ? src_f[idx] : bf2f(src_b[idx]);
    s1 += x[j];
    s2 += x[j] * x[j];
  }
#pragma unroll
  for (int off = 32; off > 0; off >>= 1) {
    s1 += __shfl_xor(s1, off);
    s2 += __shfl_xor(s2, off);
  }
  float m = s1 * (1.0f / kCM);
  float var = s2 * (1.0f / kCM) - m * m;
  float rs = rsqrtf(fmaxf(var, 0.0f) + EPSF);
#pragma unroll
  for (int j = 0; j < 4; ++j) {
    int c = 64 * j + t;
    float w = wall[head * kCM + c];
    float b = ball[head * kCM + c];
    dst[(size_t)row * kCM + c] = f2bf((x[j] - m) * rs * w + b);
  }
}

// ---------------- K3a: pack per-head qkvg weights (fp32 in, fp32 out, 128 x 256) ----------------
__global__ __launch_bounds__(256) void k_pack_wcat(const float* __restrict__ wq,
                                                   const float* __restrict__ wk,
                                                   const float* __restrict__ wv,
                                                   const float* __restrict__ wg,
                                                   float* __restrict__ Wcat, int head) {
  int idx = blockIdx.x * 256 + threadIdx.x;  // 32768
  int j = idx >> 8;
  int c = idx & 255;
  const float* src = (j < 32) ? wq : (j < 64) ? wk : (j < 96) ? wv : wg;
  int d = j & 31;
  Wcat[idx] = src[(head * kC + d) * kCM + c];
}

// ---------------- K3b: pack per-head bias weights (pair-LN folded) ----------------
__global__ __launch_bounds__(256) void k_pack_bias(const float* __restrict__ wb,
                                                   const float* __restrict__ npw,
                                                   const float* __restrict__ npb,
                                                   float* __restrict__ wbeff,
                                                   float* __restrict__ beta,
                                                   float* __restrict__ sw, int head) {
  int j = threadIdx.x;  // 256 threads, 1 block
  float sb = 0.f, ssw = 0.f;
  for (int c = 0; c < kCZ; ++c) {
    float w = wb[(head * kS + j) * kCZ + c];
    float e = w * npw[head * kCZ + c];
    wbeff[j * kCZ + c] = e;
    ssw += e;
    sb += w * npb[head * kCZ + c];
  }
  sw[j] = ssw;
  beta[j] = sb;
}

// ---------------- K4: qkvg GEMM (chunk): (49152 x 256)bf16 x (128 x 256)^T fp32 ----------------
__global__ __launch_bounds__(256) void k_gemm_qkvg(const bf16_t* __restrict__ A,
                                                   const float* __restrict__ B,
                                                   bf16_t* __restrict__ q,
                                                   bf16_t* __restrict__ k,
                                                   bf16_t* __restrict__ v,
                                                   bf16_t* __restrict__ g) {
  __shared__ float As[32][68];
  __shared__ float Bs[32][68];
  int m0 = blockIdx.x * 64;
  int n0 = blockIdx.y * 64;
  int tid = threadIdx.x;
  float acc[4][4] = {};
  for (int k0 = 0; k0 < 256; k0 += 32) {
#pragma unroll
    for (int rep = 0; rep < 2; ++rep) {
      int idx = tid + rep * 256;
      int row = idx >> 3;
      int kq = (idx & 7) * 4;
      uint2_a a2 = *(const uint2_a*)(A + (size_t)(m0 + row) * 256 + k0 + kq);
      float af[4];
      bfp2(a2.x, af + 0); bfp2(a2.y, af + 2);
      As[kq + 0][row] = af[0]; As[kq + 1][row] = af[1];
      As[kq + 2][row] = af[2]; As[kq + 3][row] = af[3];
      float4_a bv = *(const float4_a*)(B + (n0 + row) * 256 + k0 + kq);
      Bs[kq + 0][row] = bv.x; Bs[kq + 1][row] = bv.y;
      Bs[kq + 2][row] = bv.z; Bs[kq + 3][row] = bv.w;
    }
    __syncthreads();
    int tm = (tid >> 4) * 4;
    int tn = (tid & 15) * 4;
#pragma unroll
    for (int kk = 0; kk < 32; ++kk) {
      float4_a a = *(const float4_a*)&As[kk][tm];
      float4_a b = *(const float4_a*)&Bs[kk][tn];
      acc[0][0] += a.x * b.x; acc[0][1] += a.x * b.y; acc[0][2] += a.x * b.z; acc[0][3] += a.x * b.w;
      acc[1][0] += a.y * b.x; acc[1][1] += a.y * b.y; acc[1][2] += a.y * b.z; acc[1][3] += a.y * b.w;
      acc[2][0] += a.z * b.x; acc[2][1] += a.z * b.y; acc[2][2] += a.z * b.z; acc[2][3] += a.z * b.w;
      acc[3][0] += a.w * b.x; acc[3][1] += a.w * b.y; acc[3][2] += a.w * b.z; acc[3][3] += a.w * b.w;
    }
    __syncthreads();
  }
  int tm = m0 + (tid >> 4) * 4;
  int tn = n0 + (tid & 15) * 4;
  int mat = tn >> 5;
  int d0 = tn & 31;
#pragma unroll
  for (int mi = 0; mi < 4; ++mi) {
    int m = tm + mi;
#pragma unroll
    for (int ni = 0; ni < 4; ++ni) {
      float val = acc[mi][ni];
      int d = d0 + ni;
      if (mat == 0) q[(size_t)m * kC + d] = f2bf(val);
      else if (mat == 1) k[(size_t)m * kC + d] = f2bf(val);
      else if (mat == 2) v[(size_t)m * kC + d] = f2bf(val);
      else g[(size_t)m * kC + d] = f2bf(1.0f / (1.0f + __expf(-val)));
    }
  }
}

// ---------------- K5: bias GEMM (chunk): (73728 x 128)fp32 x (256 x 128)^T fp32 -> Bm bf16 ----------------
__global__ __launch_bounds__(256) void k_gemm_bias(const float* __restrict__ pair,
                                                   const float* __restrict__ Bw,
                                                   const float* __restrict__ mu,
                                                   const float* __restrict__ rstd,
                                                   const float* __restrict__ sw,
                                                   const float* __restrict__ beta,
                                                   bf16_t* __restrict__ Bm) {
  __shared__ float As[32][68];
  __shared__ float Bs[32][68];
  int m0 = blockIdx.x * 64;
  int n0 = blockIdx.y * 64;
  int tid = threadIdx.x;
  float acc[4][4] = {};
  for (int k0 = 0; k0 < 128; k0 += 32) {
#pragma unroll
    for (int rep = 0; rep < 2; ++rep) {
      int idx = tid + rep * 256;
      int row = idx >> 3;
      int kq = (idx & 7) * 4;
      float4_a av = *(const float4_a*)(pair + (size_t)(m0 + row) * kCZ + k0 + kq);
      As[kq + 0][row] = av.x; As[kq + 1][row] = av.y;
      As[kq + 2][row] = av.z; As[kq + 3][row] = av.w;
      float4_a bv = *(const float4_a*)(Bw + (n0 + row) * kCZ + k0 + kq);
      Bs[kq + 0][row] = bv.x; Bs[kq + 1][row] = bv.y;
      Bs[kq + 2][row] = bv.z; Bs[kq + 3][row] = bv.w;
    }
    __syncthreads();
    int tm = (tid >> 4) * 4;
    int tn = (tid & 15) * 4;
#pragma unroll
    for (int kk = 0; kk < 32; ++kk) {
      float4_a a = *(const float4_a*)&As[kk][tm];
      float4_a b = *(const float4_a*)&Bs[kk][tn];
      acc[0][0] += a.x * b.x; acc[0][1] += a.x * b.y; acc[0][2] += a.x * b.z; acc[0][3] += a.x * b.w;
      acc[1][0] += a.y * b.x; acc[1][1] += a.y * b.y; acc[1][2] += a.y * b.z; acc[1][3] += a.y * b.w;
      acc[2][0] += a.z * b.x; acc[2][1] += a.z * b.y; acc[2][2] += a.z * b.z; acc[2][3] += a.z * b.w;
      acc[3][0] += a.w * b.x; acc[3][1] += a.w * b.y; acc[3][2] += a.w * b.z; acc[3][3] += a.w * b.w;
    }
    __syncthreads();
  }
  int tm = m0 + (tid >> 4) * 4;
  int tn = n0 + (tid & 15) * 4;
#pragma unroll
  for (int mi = 0; mi < 4; ++mi) {
    int p = tm + mi;
    float rp = rstd[p], mp = mu[p];
#pragma unroll
    for (int ni = 0; ni < 4; ++ni) {
      int j = tn + ni;
      float val = rp * (acc[mi][ni] - mp * sw[j]) + beta[j];
      Bm[(size_t)p * kS + j] = f2bf(val);
    }
  }
}

// ---------------- K6: logits in place over Bm + online column softmax stats (chunk) ----------------
__global__ __launch_bounds__(128) void k_attn_stats(const bf16_t* __restrict__ q,
                                                    const bf16_t* __restrict__ kmat,
                                                    bf16_t* Bm,
                                                    float* __restrict__ mstat,
                                                    float* __restrict__ dinv) {
  int s = blockIdx.y;  // local s within chunk
  int t = blockIdx.x * 128 + threadIdx.x;
  __shared__ float qs[32][32];
  float kreg[32];
  const bf16_t* kp = kmat + (size_t)(s * kR + t) * kC;
#pragma unroll
  for (int c8 = 0; c8 < 32; c8 += 8) bf8load(kp + c8, kreg + c8);

  float m = -3.0e38f, d = 0.f;
  for (int rt = 0; rt < 12; ++rt) {
    int u = threadIdx.x;
    int r_l = u >> 2;
    int cq = (u & 3) * 8;
    float qf[8];
    bf8load(q + (size_t)(s * kR + rt * 32 + r_l) * kC + cq, qf);
#pragma unroll
    for (int j = 0; j < 8; ++j) qs[r_l][cq + j] = qf[j];
    __syncthreads();
#pragma unroll 4
    for (int r = 0; r < 32; ++r) {
      const float4_a* qp = (const float4_a*)&qs[r][0];
      float dot = 0.f;
#pragma unroll
      for (int c4 = 0; c4 < 8; ++c4) {
        float4_a qv = qp[c4];
        dot += qv.x * kreg[c4 * 4 + 0] + qv.y * kreg[c4 * 4 + 1] +
               qv.z * kreg[c4 * 4 + 2] + qv.w * kreg[c4 * 4 + 3];
      }
      size_t f = (size_t)s * kP + (size_t)(rt * 32 + r) * kR + t;
      float x = SCALEF * (dot + bf2f(Bm[f]));
      Bm[f] = f2bf(x);
      float mn = fmaxf(m, x);
      d = d * __expf(m - mn) + __expf(x - mn);
      m = mn;
    }
    __syncthreads();
  }
  mstat[s * kR + t] = m;
  dinv[s * kR + t] = 1.0f / d;
}

// ---------------- K7: O = g * softmax(L) @ V, write fp32 into d_out slice (chunk) ----------------
__global__ __launch_bounds__(256) void k_attn_out(const bf16_t* __restrict__ L,
                                                  const float* __restrict__ mstat,
                                                  const float* __restrict__ dinv,
                                                  const bf16_t* __restrict__ v,
                                                  const bf16_t* __restrict__ g,
                                                  float* __restrict__ o_out, int head) {
  int row = blockIdx.x;  // local row within chunk (0..49151)
  int s = row / kR, r = row % kR;
  __shared__ float p_lds[kR];
  __shared__ float part[256];
  int tid = threadIdx.x;
  for (int t = tid; t < kR; t += 256) {
    float x = bf2f(L[(size_t)s * kP + (size_t)r * kR + t]);
    p_lds[t] = __expf(x - mstat[s * kR + t]) * dinv[s * kR + t];
  }
  __syncthreads();
  int c = tid & 31, u = tid >> 5;
  float acc = 0.f;
  const bf16_t* vb = v + (size_t)(s * kR) * kC + c;
  int t0 = u * 48;
#pragma unroll 8
  for (int t = t0; t < t0 + 48; ++t) acc += p_lds[t] * bf2f(vb[(size_t)t * kC]);
  part[tid] = acc;
  __syncthreads();
  if (tid < 32) {
    float o = 0.f;
#pragma unroll
    for (int uu = 0; uu < 8; ++uu) o += part[uu * 32 + tid];
    o *= bf2f(g[(size_t)row * kC + tid]);
    o_out[(size_t)row * kCM + head * kC + tid] = o;
  }
}

// ---------------- K8: final GEMM (98304 x 256)fp32 x (256 x 256)^T fp32 + bias -> bf16 buf ----------------
__global__ __launch_bounds__(256) void k_gemm_final(const float* __restrict__ A,
                                                    const float* __restrict__ Bw,
                                                    const float* __restrict__ bias,
                                                    bf16_t* __restrict__ out) {
  __shared__ float As[32][68];
  __shared__ float Bs[32][68];
  int m0 = blockIdx.x * 64;
  int n0 = blockIdx.y * 64;
  int tid = threadIdx.x;
  float acc[4][4] = {};
  for (int k0 = 0; k0 < 256; k0 += 32) {
#pragma unroll
    for (int rep = 0; rep < 2; ++rep) {
      int idx = tid + rep * 256;
      int row = idx >> 3;
      int kq = (idx & 7) * 4;
      float4_a av = *(const float4_a*)(A + (size_t)(m0 + row) * kCM + k0 + kq);
      As[kq + 0][row] = av.x; As[kq + 1][row] = av.y;
      As[kq + 2][row] = av.z; As[kq + 3][row] = av.w;
      float4_a bv = *(const float4_a*)(Bw + (size_t)(n0 + row) * kCM + k0 + kq);
      Bs[kq + 0][row] = bv.x; Bs[kq + 1][row] = bv.y;
      Bs[kq + 2][row] = bv.z; Bs[kq + 3][row] = bv.w;
    }
    __syncthreads();
    int tm = (tid >> 4) * 4;
    int tn = (tid & 15) * 4;
#pragma unroll
    for (int kk = 0; kk < 32; ++kk) {
      float4_a a = *(const float4_a*)&As[kk][tm];
      float4_a b = *(const float4_a*)&Bs[kk][tn];
      acc[0][0] += a.x * b.x; acc[0][1] += a.x * b.y; acc[0][2] += a.x * b.z; acc[0][3] += a.x * b.w;
      acc[1][0] += a.y * b.x; acc[1][1] += a.y * b.y; acc[1][2] += a.y * b.z; acc[1][3] += a.y * b.w;
      acc[2][0] += a.z * b.x; acc[2][1] += a.z * b.y; acc[2][2] += a.z * b.z; acc[2][3] += a.z * b.w;
      acc[3][0] += a.w * b.x; acc[3][1] += a.w * b.y; acc[3][2] += a.w * b.z; acc[3][3] += a.w * b.w;
    }
    __syncthreads();
  }
  int tm = m0 + (tid >> 4) * 4;
  int tn = n0 + (tid & 15) * 4;
#pragma unroll
  for (int mi = 0; mi < 4; ++mi) {
    int m = tm + mi;
#pragma unroll
    for (int ni = 0; ni < 4; ++ni) {
      int n = tn + ni;
      out[(size_t)m * kCM + n] = f2bf(acc[mi][ni] + bias[n]);
    }
  }
}

// ---------------- K9: expand bf16 final buf -> fp32 d_out ----------------
__global__ __launch_bounds__(256) void k_expand(const bf16_t* __restrict__ in,
                                                float* __restrict__ out) {
  size_t i = ((size_t)blockIdx.x * 256 + threadIdx.x) * 8;
  float f[8];
  bf8load(in + i, f);
  *(float4_a*)(out + i)     = make_float4(f[0], f[1], f[2], f[3]);
  *(float4_a*)(out + i + 4) = make_float4(f[4], f[5], f[6], f[7]);
}

extern "C" void kernel_launch(void* const* d_in, const int* in_sizes, int n_in,
                              void* d_out, int out_size, void* d_ws, size_t ws_size,
                              hipStream_t stream) {
  const float* msa_in = (const float*)d_in[0];
  const float* pair   = (const float*)d_in[1];
  const float* nmw    = (const float*)d_in[2];
  const float* nmb    = (const float*)d_in[3];
  const float* wq     = (const float*)d_in[4];
  const float* wk     = (const float*)d_in[5];
  const float* wv     = (const float*)d_in[6];
  const float* npw    = (const float*)d_in[7];
  const float* npb    = (const float*)d_in[8];
  const float* wb     = (const float*)d_in[9];
  const float* wg     = (const float*)d_in[10];
  const float* outw   = (const float*)d_in[11];
  const float* outb   = (const float*)d_in[12];
  float* out = (float*)d_out;

  char* ws = (char*)d_ws;
  size_t off = 0;
  bf16_t* msa_cur = (bf16_t*)(ws + off); off += (size_t)kM * kCM * 2;   // 50,331,648
  size_t final_off = off;                                               // final_buf aliases Bm..g
  bf16_t* Bm      = (bf16_t*)(ws + off); off += (size_t)kPC * kS * 2;   // 37,748,736
  bf16_t* qb      = (bf16_t*)(ws + off); off += (size_t)kMC * kC * 2;   // 3,145,728
  bf16_t* kb      = (bf16_t*)(ws + off); off += (size_t)kMC * kC * 2;
  bf16_t* vb      = (bf16_t*)(ws + off); off += (size_t)kMC * kC * 2;
  bf16_t* gb      = (bf16_t*)(ws + off); off += (size_t)kMC * kC * 2;
  float* mstat    = (float*)(ws + off);  off += (size_t)kMC * 4;        // 196,608
  float* dinv     = (float*)(ws + off);  off += (size_t)kMC * 4;
  float* mu_p     = (float*)(ws + off);  off += (size_t)kP * 4;         // 589,824
  float* rstd_p   = (float*)(ws + off);  off += (size_t)kP * 4;
  float* Wcat     = (float*)(ws + off);  off += (size_t)128 * 256 * 4;  // 131,072
  float* wbeff    = (float*)(ws + off);  off += (size_t)256 * 128 * 4;
  float* beta     = (float*)(ws + off);  off += 1024;
  float* swv      = (float*)(ws + off);  off += 1024;
  bf16_t* final_buf = (bf16_t*)(ws + final_off);  // 50,331,648 B (Bm..g dead at final)
  // total ~97.8 MiB

  k_pair_stats<<<kP, 64, 0, stream>>>(pair, mu_p, rstd_p);

  for (int h = 0; h < kH; ++h) {
    k_msa_ln<<<kM, 64, 0, stream>>>(msa_in, msa_cur, msa_cur, nmw, nmb, h, h == 0 ? 1 : 0);
    k_pack_wcat<<<128, 256, 0, stream>>>(wq, wk, wv, wg, Wcat, h);
    k_pack_bias<<<1, 256, 0, stream>>>(wb, npw, npb, wbeff, beta, swv, h);
    for (int c = 0; c < kNCH; ++c) {
      const bf16_t* msa_ch = msa_cur + (size_t)c * kMC * kCM;
      const float* pair_ch = pair + (size_t)c * kPC * kCZ;
      k_gemm_qkvg<<<dim3(kMC / 64, 2), 256, 0, stream>>>(msa_ch, Wcat, qb, kb, vb, gb);
      k_gemm_bias<<<dim3(kPC / 64, 4), 256, 0, stream>>>(pair_ch, wbeff,
                                                         mu_p + (size_t)c * kPC,
                                                         rstd_p + (size_t)c * kPC,
                                                         swv, beta, Bm);
      k_attn_stats<<<dim3(3, kSC), 128, 0, stream>>>(qb, kb, Bm, mstat, dinv);
      k_attn_out<<<kMC, 256, 0, stream>>>(Bm, mstat, dinv, vb, gb,
                                          out + (size_t)c * kMC * kCM, h);
    }
  }

  k_gemm_final<<<dim3(kM / 64, 4), 256, 0, stream>>>(out, outw, outb, final_buf);
  k_expand<<<kM * kCM / 2048, 256, 0, stream>>>(final_buf, out);
}

// Round 4
// 2210.729 us; speedup vs baseline: 2.5719x; 2.5719x over previous
//
#include <hip/hip_runtime.h>

typedef unsigned short bf16_t;
typedef uint4  __attribute__((may_alias)) uint4_a;
typedef float4 __attribute__((may_alias)) float4_a;
typedef short bf16x8 __attribute__((ext_vector_type(8)));
typedef bf16x8 __attribute__((may_alias)) bf16x8_a;
typedef float f32x4 __attribute__((ext_vector_type(4)));

#define MFMA16(a, b, c) __builtin_amdgcn_mfma_f32_16x16x32_bf16((a), (b), (c), 0, 0, 0)

constexpr int kS  = 256;
constexpr int kR  = 384;
constexpr int kCM = 256;
constexpr int kCZ = 128;
constexpr int kC  = 32;
constexpr int kH  = 8;
constexpr int kP  = kR * kR;        // 147456
constexpr int kM  = kS * kR;        // 98304
constexpr int kSC = 64;             // s per chunk
constexpr int kNCH = kS / kSC;      // 4 chunks
constexpr int kMC = kSC * kR;       // 24576 msa rows per chunk
constexpr int kPC = kSC * kP / kS;  // 36864 pair rows per chunk

#define EPSF 1e-5f
#define SCALEF 0.17677669529663687f

__device__ __forceinline__ float bf2f(bf16_t u) {
  return __uint_as_float(((unsigned int)u) << 16);
}
__device__ __forceinline__ bf16_t f2bf(float f) {
  unsigned int u = __float_as_uint(f);
  u += 0x7fffu + ((u >> 16) & 1u);
  return (bf16_t)(u >> 16);
}

// ---------------- pair stats (fp32) ----------------
__global__ __launch_bounds__(64) void k_pair_stats(const float* __restrict__ pair,
                                                   float* __restrict__ mu,
                                                   float* __restrict__ rstd) {
  int p = blockIdx.x;
  int t = threadIdx.x;
  float x0 = pair[(size_t)p * kCZ + t];
  float x1 = pair[(size_t)p * kCZ + 64 + t];
  float s1 = x0 + x1;
  float s2 = x0 * x0 + x1 * x1;
#pragma unroll
  for (int off = 32; off > 0; off >>= 1) {
    s1 += __shfl_xor(s1, off);
    s2 += __shfl_xor(s2, off);
  }
  if (t == 0) {
    float m = s1 * (1.0f / kCZ);
    float v = s2 * (1.0f / kCZ) - m * m;
    mu[p] = m;
    rstd[p] = rsqrtf(fmaxf(v, 0.0f) + EPSF);
  }
}

// ---------------- pair fp32 -> bf16 ----------------
__global__ __launch_bounds__(256) void k_pair_cvt(const float* __restrict__ in,
                                                  bf16_t* __restrict__ out) {
  size_t i = ((size_t)blockIdx.x * 256 + threadIdx.x) * 8;
  float4_a a = *(const float4_a*)(in + i);
  float4_a b = *(const float4_a*)(in + i + 4);
  bf16_t h[8] = {f2bf(a.x), f2bf(a.y), f2bf(a.z), f2bf(a.w),
                 f2bf(b.x), f2bf(b.y), f2bf(b.z), f2bf(b.w)};
  uint4 u;
  u.x = (unsigned)h[0] | ((unsigned)h[1] << 16);
  u.y = (unsigned)h[2] | ((unsigned)h[3] << 16);
  u.z = (unsigned)h[4] | ((unsigned)h[5] << 16);
  u.w = (unsigned)h[6] | ((unsigned)h[7] << 16);
  *(uint4_a*)(out + i) = u;
}

// ---------------- msa LN (fp32/bf16 src -> bf16 dst) ----------------
__global__ __launch_bounds__(64) void k_msa_ln(const float* __restrict__ src_f,
                                               const bf16_t* __restrict__ src_b,
                                               bf16_t* __restrict__ dst,
                                               const float* __restrict__ wall,
                                               const float* __restrict__ ball,
                                               int head, int first) {
  int row = blockIdx.x;
  int t = threadIdx.x;
  float x[4];
  float s1 = 0.f, s2 = 0.f;
#pragma unroll
  for (int j = 0; j < 4; ++j) {
    size_t idx = (size_t)row * kCM + 64 * j + t;
    x[j] = first ? src_f[idx] : bf2f(src_b[idx]);
    s1 += x[j];
    s2 += x[j] * x[j];
  }
#pragma unroll
  for (int off = 32; off > 0; off >>= 1) {
    s1 += __shfl_xor(s1, off);
    s2 += __shfl_xor(s2, off);
  }
  float m = s1 * (1.0f / kCM);
  float var = s2 * (1.0f / kCM) - m * m;
  float rs = rsqrtf(fmaxf(var, 0.0f) + EPSF);
#pragma unroll
  for (int j = 0; j < 4; ++j) {
    int c = 64 * j + t;
    dst[(size_t)row * kCM + c] = f2bf((x[j] - m) * rs * wall[head * kCM + c] + ball[head * kCM + c]);
  }
}

// ---------------- pack qkvg weights -> bf16 (128 x 256) ----------------
__global__ __launch_bounds__(256) void k_pack_wcat(const float* __restrict__ wq,
                                                   const float* __restrict__ wk,
                                                   const float* __restrict__ wv,
                                                   const float* __restrict__ wg,
                                                   bf16_t* __restrict__ Wcat, int head) {
  int idx = blockIdx.x * 256 + threadIdx.x;  // 32768
  int j = idx >> 8;
  int c = idx & 255;
  const float* src = (j < 32) ? wq : (j < 64) ? wk : (j < 96) ? wv : wg;
  int d = j & 31;
  Wcat[idx] = f2bf(src[(head * kC + d) * kCM + c]);
}

// ---------------- pack bias weights (pair-LN folded) -> bf16 ----------------
__global__ __launch_bounds__(256) void k_pack_bias(const float* __restrict__ wb,
                                                   const float* __restrict__ npw,
                                                   const float* __restrict__ npb,
                                                   bf16_t* __restrict__ wbeff,
                                                   float* __restrict__ beta,
                                                   float* __restrict__ sw, int head) {
  int j = threadIdx.x;  // 256 threads, 1 block
  float sb = 0.f, ssw = 0.f;
  for (int c = 0; c < kCZ; ++c) {
    float w = wb[(head * kS + j) * kCZ + c];
    float e = w * npw[head * kCZ + c];
    wbeff[j * kCZ + c] = f2bf(e);
    ssw += e;
    sb += w * npb[head * kCZ + c];
  }
  sw[j] = ssw;
  beta[j] = sb;
}

// ---------------- pack out_w -> bf16 ----------------
__global__ __launch_bounds__(256) void k_pack_outw(const float* __restrict__ in,
                                                   bf16_t* __restrict__ out) {
  int i = blockIdx.x * 256 + threadIdx.x;  // 65536
  out[i] = f2bf(in[i]);
}

// ---------------- qkvg GEMM MFMA: (kMC x 256) x (128 x 256)^T ----------------
__global__ __launch_bounds__(256) void k_gemm_qkvg_mx(const bf16_t* __restrict__ A,
                                                      const bf16_t* __restrict__ B,
                                                      bf16_t* __restrict__ q,
                                                      bf16_t* __restrict__ k,
                                                      bf16_t* __restrict__ v,
                                                      bf16_t* __restrict__ g) {
  __shared__ bf16_t As[128 * 32];
  __shared__ bf16_t Bs[128 * 32];
  int m0 = blockIdx.x * 128;
  int tid = threadIdx.x;
  int w = tid >> 6, L = tid & 63, l15 = L & 15, q4 = L >> 4;
  int wm = w >> 1, wn = w & 1;
  f32x4 acc[4][4] = {};
  for (int k0 = 0; k0 < 256; k0 += 32) {
#pragma unroll
    for (int rep = 0; rep < 2; ++rep) {
      int idx = tid + rep * 256;
      int row = idx >> 2, sg = idx & 3;
      *(uint4_a*)&As[row * 32 + sg * 8] = *(const uint4_a*)(A + (size_t)(m0 + row) * 256 + k0 + sg * 8);
      *(uint4_a*)&Bs[row * 32 + sg * 8] = *(const uint4_a*)(B + (size_t)row * 256 + k0 + sg * 8);
    }
    __syncthreads();
    bf16x8 af[4], bfr[4];
#pragma unroll
    for (int mt = 0; mt < 4; ++mt) af[mt] = *(const bf16x8_a*)&As[(wm * 64 + mt * 16 + l15) * 32 + q4 * 8];
#pragma unroll
    for (int nt = 0; nt < 4; ++nt) bfr[nt] = *(const bf16x8_a*)&Bs[(wn * 64 + nt * 16 + l15) * 32 + q4 * 8];
#pragma unroll
    for (int mt = 0; mt < 4; ++mt)
#pragma unroll
      for (int nt = 0; nt < 4; ++nt) acc[mt][nt] = MFMA16(af[mt], bfr[nt], acc[mt][nt]);
    __syncthreads();
  }
#pragma unroll
  for (int mt = 0; mt < 4; ++mt)
#pragma unroll
    for (int nt = 0; nt < 4; ++nt) {
      int n = wn * 64 + nt * 16 + l15;
      int mat = n >> 5, d = n & 31;
      bf16_t* tgt = (mat == 0) ? q : (mat == 1) ? k : (mat == 2) ? v : g;
#pragma unroll
      for (int i = 0; i < 4; ++i) {
        int m = m0 + wm * 64 + mt * 16 + q4 * 4 + i;
        float val = acc[mt][nt][i];
        if (mat == 3) val = 1.0f / (1.0f + __expf(-val));
        tgt[(size_t)m * kC + d] = f2bf(val);
      }
    }
}

// ---------------- bias GEMM MFMA: (kPC x 128) x (256 x 128)^T -> Bm bf16 ----------------
__global__ __launch_bounds__(256) void k_gemm_bias_mx(const bf16_t* __restrict__ A,
                                                      const bf16_t* __restrict__ B,
                                                      const float* __restrict__ mu,
                                                      const float* __restrict__ rstd,
                                                      const float* __restrict__ sw,
                                                      const float* __restrict__ beta,
                                                      bf16_t* __restrict__ Bm) {
  __shared__ bf16_t As[128 * 32];
  __shared__ bf16_t Bs[128 * 32];
  int m0 = blockIdx.x * 128;
  int n0 = blockIdx.y * 128;
  int tid = threadIdx.x;
  int w = tid >> 6, L = tid & 63, l15 = L & 15, q4 = L >> 4;
  int wm = w >> 1, wn = w & 1;
  f32x4 acc[4][4] = {};
  for (int k0 = 0; k0 < 128; k0 += 32) {
#pragma unroll
    for (int rep = 0; rep < 2; ++rep) {
      int idx = tid + rep * 256;
      int row = idx >> 2, sg = idx & 3;
      *(uint4_a*)&As[row * 32 + sg * 8] = *(const uint4_a*)(A + (size_t)(m0 + row) * 128 + k0 + sg * 8);
      *(uint4_a*)&Bs[row * 32 + sg * 8] = *(const uint4_a*)(B + (size_t)(n0 + row) * 128 + k0 + sg * 8);
    }
    __syncthreads();
    bf16x8 af[4], bfr[4];
#pragma unroll
    for (int mt = 0; mt < 4; ++mt) af[mt] = *(const bf16x8_a*)&As[(wm * 64 + mt * 16 + l15) * 32 + q4 * 8];
#pragma unroll
    for (int nt = 0; nt < 4; ++nt) bfr[nt] = *(const bf16x8_a*)&Bs[(wn * 64 + nt * 16 + l15) * 32 + q4 * 8];
#pragma unroll
    for (int mt = 0; mt < 4; ++mt)
#pragma unroll
      for (int nt = 0; nt < 4; ++nt) acc[mt][nt] = MFMA16(af[mt], bfr[nt], acc[mt][nt]);
    __syncthreads();
  }
#pragma unroll
  for (int mt = 0; mt < 4; ++mt)
#pragma unroll
    for (int i = 0; i < 4; ++i) {
      int m = m0 + wm * 64 + mt * 16 + q4 * 4 + i;
      float mp = mu[m], rp = rstd[m];
#pragma unroll
      for (int nt = 0; nt < 4; ++nt) {
        int n = n0 + wn * 64 + nt * 16 + l15;
        float val = rp * (acc[mt][nt][i] - mp * sw[n]) + beta[n];
        Bm[(size_t)m * kS + n] = f2bf(val);
      }
    }
}

// ---------------- logits: QK^T MFMA + bias (in acc) + column softmax -> a (in-place Bm) ----------------
__global__ __launch_bounds__(256) void k_logits(const bf16_t* __restrict__ q,
                                                const bf16_t* __restrict__ kmat,
                                                bf16_t* __restrict__ Bm) {
  int s = blockIdx.y;
  int t0 = blockIdx.x * 64;
  int tid = threadIdx.x;
  int w = tid >> 6, L = tid & 63, l15 = L & 15, q4 = L >> 4;
  __shared__ float red[4][64];
  __shared__ float msh[64], dish[64];
  bf16_t* bmS = Bm + (size_t)s * kP;
  f32x4 acc[6][4];
  // preload bias into accumulator (C/D layout)
#pragma unroll
  for (int rt = 0; rt < 6; ++rt)
#pragma unroll
    for (int nt = 0; nt < 4; ++nt)
#pragma unroll
      for (int i = 0; i < 4; ++i) {
        int r = w * 96 + rt * 16 + q4 * 4 + i;
        int t = t0 + nt * 16 + l15;
        acc[rt][nt][i] = bf2f(bmS[(size_t)r * kR + t]);
      }
  const bf16_t* qs = q + (size_t)s * kR * kC;
  const bf16_t* ks = kmat + (size_t)s * kR * kC;
  bf16x8 bfr[4];
#pragma unroll
  for (int nt = 0; nt < 4; ++nt)
    bfr[nt] = *(const bf16x8_a*)(ks + (size_t)(t0 + nt * 16 + l15) * kC + q4 * 8);
#pragma unroll
  for (int rt = 0; rt < 6; ++rt) {
    bf16x8 af = *(const bf16x8_a*)(qs + (size_t)(w * 96 + rt * 16 + l15) * kC + q4 * 8);
#pragma unroll
    for (int nt = 0; nt < 4; ++nt) acc[rt][nt] = MFMA16(af, bfr[nt], acc[rt][nt]);
  }
  // scale
#pragma unroll
  for (int rt = 0; rt < 6; ++rt)
#pragma unroll
    for (int nt = 0; nt < 4; ++nt) acc[rt][nt] *= SCALEF;
  // column (over r) max
  float mx[4] = {-3.0e38f, -3.0e38f, -3.0e38f, -3.0e38f};
#pragma unroll
  for (int rt = 0; rt < 6; ++rt)
#pragma unroll
    for (int nt = 0; nt < 4; ++nt)
#pragma unroll
      for (int i = 0; i < 4; ++i) mx[nt] = fmaxf(mx[nt], acc[rt][nt][i]);
#pragma unroll
  for (int nt = 0; nt < 4; ++nt) {
    mx[nt] = fmaxf(mx[nt], __shfl_xor(mx[nt], 16));
    mx[nt] = fmaxf(mx[nt], __shfl_xor(mx[nt], 32));
  }
  if (L < 16) {
#pragma unroll
    for (int nt = 0; nt < 4; ++nt) red[w][nt * 16 + L] = mx[nt];
  }
  __syncthreads();
  if (tid < 64) {
    float m = fmaxf(fmaxf(red[0][tid], red[1][tid]), fmaxf(red[2][tid], red[3][tid]));
    msh[tid] = m;
  }
  __syncthreads();
  float mt_[4];
#pragma unroll
  for (int nt = 0; nt < 4; ++nt) mt_[nt] = msh[nt * 16 + l15];
  float sm[4] = {0.f, 0.f, 0.f, 0.f};
#pragma unroll
  for (int rt = 0; rt < 6; ++rt)
#pragma unroll
    for (int nt = 0; nt < 4; ++nt)
#pragma unroll
      for (int i = 0; i < 4; ++i) {
        float e = __expf(acc[rt][nt][i] - mt_[nt]);
        acc[rt][nt][i] = e;
        sm[nt] += e;
      }
#pragma unroll
  for (int nt = 0; nt < 4; ++nt) {
    sm[nt] += __shfl_xor(sm[nt], 16);
    sm[nt] += __shfl_xor(sm[nt], 32);
  }
  __syncthreads();
  if (L < 16) {
#pragma unroll
    for (int nt = 0; nt < 4; ++nt) red[w][nt * 16 + L] = sm[nt];
  }
  __syncthreads();
  if (tid < 64) {
    float d = red[0][tid] + red[1][tid] + red[2][tid] + red[3][tid];
    dish[tid] = 1.0f / d;
  }
  __syncthreads();
  float di[4];
#pragma unroll
  for (int nt = 0; nt < 4; ++nt) di[nt] = dish[nt * 16 + l15];
  // write probabilities a (bf16) in place
#pragma unroll
  for (int rt = 0; rt < 6; ++rt)
#pragma unroll
    for (int nt = 0; nt < 4; ++nt)
#pragma unroll
      for (int i = 0; i < 4; ++i) {
        int r = w * 96 + rt * 16 + q4 * 4 + i;
        int t = t0 + nt * 16 + l15;
        bmS[(size_t)r * kR + t] = f2bf(acc[rt][nt][i] * di[nt]);
      }
}

// ---------------- PV: o = g * (a @ v) via MFMA, fp32 out into d_out slice ----------------
__global__ __launch_bounds__(256) void k_pv(const bf16_t* __restrict__ Am,
                                            const bf16_t* __restrict__ v,
                                            const bf16_t* __restrict__ g,
                                            float* __restrict__ o, int head) {
  int s = blockIdx.y;
  int r0 = blockIdx.x * 64;
  int tid = threadIdx.x;
  int w = tid >> 6, L = tid & 63, l15 = L & 15, q4 = L >> 4;
  __shared__ bf16_t vT[32 * 392];  // [c][t], padded stride
  // stage v transposed
#pragma unroll
  for (int rep = 0; rep < 6; ++rep) {
    int idx = tid + rep * 256;  // 1536
    int t = idx >> 2, sg = idx & 3;
    union { uint4 u; bf16_t h[8]; } uu;
    uu.u = *(const uint4_a*)(v + (size_t)(s * kR + t) * kC + sg * 8);
#pragma unroll
    for (int j = 0; j < 8; ++j) vT[(sg * 8 + j) * 392 + t] = uu.h[j];
  }
  __syncthreads();
  const bf16_t* aS = Am + (size_t)s * kP + (size_t)(r0 + 16 * w + l15) * kR;
  f32x4 acc[2] = {};
#pragma unroll
  for (int kk = 0; kk < 12; ++kk) {
    bf16x8 af = *(const bf16x8_a*)(aS + kk * 32 + q4 * 8);
#pragma unroll
    for (int nt = 0; nt < 2; ++nt) {
      bf16x8 bfv = *(const bf16x8_a*)&vT[(nt * 16 + l15) * 392 + kk * 32 + q4 * 8];
      acc[nt] = MFMA16(af, bfv, acc[nt]);
    }
  }
#pragma unroll
  for (int nt = 0; nt < 2; ++nt)
#pragma unroll
    for (int i = 0; i < 4; ++i) {
      int r = r0 + 16 * w + q4 * 4 + i;
      int c = nt * 16 + l15;
      float val = acc[nt][i] * bf2f(g[(size_t)(s * kR + r) * kC + c]);
      o[(size_t)(s * kR + r) * kCM + head * kC + c] = val;
    }
}

// ---------------- final GEMM: (kM x 256 fp32 -> hi/lo bf16) x (256 x 256)^T bf16, in-place d_out ----------------
__global__ __launch_bounds__(256) void k_gemm_final_mx(const float* __restrict__ OA,
                                                       const bf16_t* __restrict__ Bw,
                                                       const float* __restrict__ bias,
                                                       float* __restrict__ out) {
  __shared__ bf16_t As[2 * 64 * 32];  // [half][row][k]
  __shared__ bf16_t Bs[256 * 32];
  int m0 = blockIdx.x * 64;
  int tid = threadIdx.x;
  int w = tid >> 6, L = tid & 63, l15 = L & 15, q4 = L >> 4;
  f32x4 acc[4][4] = {};  // [mt][nt]
  for (int kc = 0; kc < 256; kc += 32) {
    {
      int row = tid >> 2, sg = tid & 3;
      const float* src = OA + (size_t)(m0 + row) * kCM + kc + sg * 8;
      float4_a f0 = *(const float4_a*)src;
      float4_a f1 = *(const float4_a*)(src + 4);
      float ff[8] = {f0.x, f0.y, f0.z, f0.w, f1.x, f1.y, f1.z, f1.w};
      uint4 uh, ul;
      bf16_t hi[8], lo[8];
#pragma unroll
      for (int j = 0; j < 8; ++j) {
        hi[j] = f2bf(ff[j]);
        lo[j] = f2bf(ff[j] - bf2f(hi[j]));
      }
      uh.x = (unsigned)hi[0] | ((unsigned)hi[1] << 16); uh.y = (unsigned)hi[2] | ((unsigned)hi[3] << 16);
      uh.z = (unsigned)hi[4] | ((unsigned)hi[5] << 16); uh.w = (unsigned)hi[6] | ((unsigned)hi[7] << 16);
      ul.x = (unsigned)lo[0] | ((unsigned)lo[1] << 16); ul.y = (unsigned)lo[2] | ((unsigned)lo[3] << 16);
      ul.z = (unsigned)lo[4] | ((unsigned)lo[5] << 16); ul.w = (unsigned)lo[6] | ((unsigned)lo[7] << 16);
      *(uint4_a*)&As[row * 32 + sg * 8] = uh;
      *(uint4_a*)&As[2048 + row * 32 + sg * 8] = ul;
    }
#pragma unroll
    for (int rep = 0; rep < 4; ++rep) {
      int idx = tid + rep * 256;
      int row = idx >> 2, sg = idx & 3;
      *(uint4_a*)&Bs[row * 32 + sg * 8] = *(const uint4_a*)(Bw + (size_t)row * kCM + kc + sg * 8);
    }
    __syncthreads();
    bf16x8 bfr[4];
#pragma unroll
    for (int nt = 0; nt < 4; ++nt) bfr[nt] = *(const bf16x8_a*)&Bs[(w * 64 + nt * 16 + l15) * 32 + q4 * 8];
#pragma unroll
    for (int half = 0; half < 2; ++half)
#pragma unroll
      for (int mt = 0; mt < 4; ++mt) {
        bf16x8 af = *(const bf16x8_a*)&As[half * 2048 + (mt * 16 + l15) * 32 + q4 * 8];
#pragma unroll
        for (int nt = 0; nt < 4; ++nt) acc[mt][nt] = MFMA16(af, bfr[nt], acc[mt][nt]);
      }
    __syncthreads();
  }
#pragma unroll
  for (int mt = 0; mt < 4; ++mt)
#pragma unroll
    for (int nt = 0; nt < 4; ++nt) {
      int n = w * 64 + nt * 16 + l15;
      float bn = bias[n];
#pragma unroll
      for (int i = 0; i < 4; ++i) {
        int m = m0 + mt * 16 + q4 * 4 + i;
        out[(size_t)m * kCM + n] = acc[mt][nt][i] + bn;
      }
    }
}

extern "C" void kernel_launch(void* const* d_in, const int* in_sizes, int n_in,
                              void* d_out, int out_size, void* d_ws, size_t ws_size,
                              hipStream_t stream) {
  (void)in_sizes; (void)n_in; (void)out_size; (void)ws_size;
  const float* msa_in = (const float*)d_in[0];
  const float* pair   = (const float*)d_in[1];
  const float* nmw    = (const float*)d_in[2];
  const float* nmb    = (const float*)d_in[3];
  const float* wq     = (const float*)d_in[4];
  const float* wk     = (const float*)d_in[5];
  const float* wv     = (const float*)d_in[6];
  const float* npw    = (const float*)d_in[7];
  const float* npb    = (const float*)d_in[8];
  const float* wb     = (const float*)d_in[9];
  const float* wg     = (const float*)d_in[10];
  const float* outw   = (const float*)d_in[11];
  const float* outb   = (const float*)d_in[12];
  float* out = (float*)d_out;

  char* ws = (char*)d_ws;
  size_t off = 0;
  bf16_t* msa_cur = (bf16_t*)(ws + off); off += (size_t)kM * kCM * 2;    // 50,331,648
  bf16_t* pair_bf = (bf16_t*)(ws + off); off += (size_t)kP * kCZ * 2;    // 37,748,736
  bf16_t* Bm      = (bf16_t*)(ws + off); off += (size_t)kPC * kS * 2;    // 18,874,368
  bf16_t* qb      = (bf16_t*)(ws + off); off += (size_t)kMC * kC * 2;    // 1,572,864
  bf16_t* kb      = (bf16_t*)(ws + off); off += (size_t)kMC * kC * 2;
  bf16_t* vb      = (bf16_t*)(ws + off); off += (size_t)kMC * kC * 2;
  bf16_t* gb      = (bf16_t*)(ws + off); off += (size_t)kMC * kC * 2;
  float* mu_p     = (float*)(ws + off);  off += (size_t)kP * 4;          // 589,824
  float* rstd_p   = (float*)(ws + off);  off += (size_t)kP * 4;
  bf16_t* Wcat_bf = (bf16_t*)(ws + off); off += (size_t)128 * 256 * 2;
  bf16_t* wbef_bf = (bf16_t*)(ws + off); off += (size_t)256 * 128 * 2;
  bf16_t* outw_bf = (bf16_t*)(ws + off); off += (size_t)256 * 256 * 2;
  float* beta     = (float*)(ws + off);  off += 1024;
  float* swv      = (float*)(ws + off);  off += 1024;
  // total ~115 MB

  k_pair_stats<<<kP, 64, 0, stream>>>(pair, mu_p, rstd_p);
  k_pair_cvt<<<kP * kCZ / 2048, 256, 0, stream>>>(pair, pair_bf);
  k_pack_outw<<<256, 256, 0, stream>>>(outw, outw_bf);

  for (int h = 0; h < kH; ++h) {
    k_msa_ln<<<kM, 64, 0, stream>>>(msa_in, msa_cur, msa_cur, nmw, nmb, h, h == 0 ? 1 : 0);
    k_pack_wcat<<<128, 256, 0, stream>>>(wq, wk, wv, wg, Wcat_bf, h);
    k_pack_bias<<<1, 256, 0, stream>>>(wb, npw, npb, wbef_bf, beta, swv, h);
    for (int c = 0; c < kNCH; ++c) {
      const bf16_t* msa_ch  = msa_cur + (size_t)c * kMC * kCM;
      const bf16_t* pair_ch = pair_bf + (size_t)c * kPC * kCZ;
      k_gemm_qkvg_mx<<<dim3(kMC / 128, 1), 256, 0, stream>>>(msa_ch, Wcat_bf, qb, kb, vb, gb);
      k_gemm_bias_mx<<<dim3(kPC / 128, 2), 256, 0, stream>>>(pair_ch, wbef_bf,
                                                             mu_p + (size_t)c * kPC,
                                                             rstd_p + (size_t)c * kPC,
                                                             swv, beta, Bm);
      k_logits<<<dim3(6, kSC), 256, 0, stream>>>(qb, kb, Bm);
      k_pv<<<dim3(6, kSC), 256, 0, stream>>>(Bm, vb, gb, out + (size_t)c * kMC * kCM, h);
    }
  }

  k_gemm_final_mx<<<kM / 64, 256, 0, stream>>>(out, outw_bf, outb, out);
}